// Round 15
// baseline (213.202 us; speedup 1.0000x reference)
//
#include <hip/hip_runtime.h>
#include <stdint.h>

// ---------------- problem constants ----------------
#define S_LEN 256
#define OUT1  262      // S + 7 - 1
#define K1SEL 131      // ceil((2-1)/2 * 262)
#define OUT2  135      // 131 + 5 - 1
// ws layout (floats)
#define W1T_OFF 0          // w1t[d][k][f]      64*7*8   = 3584
#define W2T_OFF 3584       // w2t[g][ic][k][f2] 32*8*5*16= 20480
#define B1C_OFF 24064      // b1c[r2][f]        32*8
#define B2C_OFF 24320      // b2c[r3][f2]       16*16
#define WREG    1120       // floats per wave LDS region

typedef float v2f __attribute__((ext_vector_type(2)));
__device__ __forceinline__ v2f fma2(v2f a, v2f b, v2f c) {
    return __builtin_elementwise_fma(a, b, c);   // -> v_pk_fma_f32 (exact fma/lane)
}

__device__ __forceinline__ int lane_prefix(unsigned long long m) {
    return __builtin_amdgcn_mbcnt_hi((uint32_t)(m >> 32),
           __builtin_amdgcn_mbcnt_lo((uint32_t)m, 0));
}
__device__ __forceinline__ uint32_t f2ord(float x) {
    uint32_t b = __float_as_uint(x);
    return (b & 0x80000000u) ? ~b : (b | 0x80000000u);
}
__device__ __forceinline__ float ord2f(uint32_t s) {
    uint32_t b = (s & 0x80000000u) ? (s & 0x7FFFFFFFu) : ~s;
    return __uint_as_float(b);
}
// tanh via hw rcp: (e-1)*rcp(e+1), e=exp(2x). applied strictly AFTER selection.
__device__ __forceinline__ float fast_tanh(float x) {
    float e = __expf(2.0f * x);
    return (e - 1.0f) * __builtin_amdgcn_rcpf(e + 1.0f);
}
typedef unsigned long long u64;
__device__ __forceinline__ u64 shflx64(u64 v, int m) {
    uint32_t lo = (uint32_t)__shfl_xor((int)(uint32_t)v, m, 64);
    uint32_t hi = (uint32_t)__shfl_xor((int)(uint32_t)(v >> 32), m, 64);
    return ((u64)hi << 32) | lo;
}
__device__ __forceinline__ u64 maxu64(u64 a, u64 b) { return a > b ? a : b; }
__device__ __forceinline__ u64 minu64(u64 a, u64 b) { return a < b ? a : b; }

// ------------- prep: transpose weights / fold biases into ws; init out with bias -------------
extern "C" __global__ void dcnn_prep(const float* __restrict__ w1, const float* __restrict__ b1,
                                     const float* __restrict__ w2, const float* __restrict__ b2,
                                     const float* __restrict__ fcb, float* __restrict__ out,
                                     float* __restrict__ ws) {
    int i = blockIdx.x * 256 + threadIdx.x;   // 96*256 == 24576
    if (i < 3072) out[i] = fcb[i % 6];        // out[s*6+n] = fcb[n]
    if (i < W2T_OFF) {                        // w1t[d][k][f] = w1[(d*8+f)*7 + k]
        int d = i / 56, r = i % 56, k = r / 8, f = r % 8;
        ws[i] = w1[(d * 8 + f) * 7 + k];
    } else if (i < B1C_OFF) {                 // w2t[g][ic][k][f2] = w2[((g*16+f2)*8+ic)*5+k]
        int q = i - W2T_OFF;
        int g = q / 640, r = q % 640;
        int ic = r / 80, r2 = r % 80;
        int k = r2 / 16, f2 = r2 % 16;
        ws[i] = w2[((g * 16 + f2) * 8 + ic) * 5 + k];
    } else if (i < B2C_OFF) {                 // b1c[r2][f] = b1[2r2*8+f] + b1[(2r2+1)*8+f]
        int q = i - B1C_OFF;
        int r2 = q / 8, f = q % 8;
        ws[i] = b1[(2 * r2) * 8 + f] + b1[(2 * r2 + 1) * 8 + f];
    } else {                                  // b2c[r3][f2]
        int q = i - B2C_OFF;
        int r3 = q / 16, f2 = q % 16;
        ws[i] = b2[(2 * r3) * 16 + f2] + b2[(2 * r3 + 1) * 16 + f2];
    }
}

// ------------- main: one wave = one (slice, rs-half) task; R12/R14 structure -------------
// Block = 256 thr (4 waves) = 2 slices x 2 rs-halves of ONE sample; grid 4096.
// R15: retry 4-way channel interleave in the radix select. R8's 4-way failed
// because waves_per_eu(6,8) squeezed to 40 VGPR and u[4][5] spilled; under the
// (4,8) budget (VGPR cap 128, currently 44) the +20 regs fit spill-free. Two
// serial 16-step chains instead of four; 20 independent ballots per step fill
// the VALU pipe while SALU popcount-sums drain. Keep-set semantics unchanged.
// R14: ge-tracking invariant (no-refine <=> ge==K => keep = u>=pre, plain
// compaction). R13: smaller blocks don't raise occupancy (reverted). R12:
// rcp-tanh + dense post-pass. R11: v_pk_fma_f32 convs. R3: all indices
// compile-time (runtime index => array to scratch).
extern "C" __global__
__attribute__((amdgpu_flat_work_group_size(256, 256), amdgpu_waves_per_eu(4, 8)))
void dcnn_main(const int* __restrict__ x, const float* __restrict__ emb,
               const float* __restrict__ fcw, const float* __restrict__ ws,
               float* __restrict__ out) {
    __shared__ float uni[4 * WREG];       // 17920 B
    __shared__ int   xs[S_LEN];           // 1 KB
    __shared__ float p2loc[128];          // this block's 128 FC features (raw, pre-tanh)
    __shared__ float fred[2][6];

    const int tid    = threadIdx.x;
    const int lane   = tid & 63;
    const int wv     = __builtin_amdgcn_readfirstlane(tid >> 6);  // 0..3
    const int sample = blockIdx.x >> 3;
    const int q8     = blockIdx.x & 7;
    const int sl     = q8 * 2 + (wv >> 1);   // global slice r3 in [0,16)
    const int rs     = wv & 1;               // which half of the fold pair

    const float* w1t = ws + W1T_OFF;
    const float* w2t = ws + W2T_OFF;
    const float* b1c = ws + B1C_OFF;
    const float* b2c = ws + B2C_OFF;

    xs[tid] = x[sample * S_LEN + tid];
    __syncthreads();

    float*  reg   = uni + wv * WREG;
    float2* rowsW = (float2*)reg;          // 272 float2 = 544 floats
    float*  p1w   = reg;                   // [f:8][140]

    // ---- guards + stage 2 embedding rows (d = 4sl+2rs, +1) as float2 per j ----
    if (lane < 8) {
        rowsW[lane]       = make_float2(0.f, 0.f);
        rowsW[264 + lane] = make_float2(0.f, 0.f);
    }
    const int dbase = 4 * sl + 2 * rs;
#pragma unroll
    for (int m = 0; m < 4; ++m) {
        int j  = lane + 64 * m;            // input pos 0..255
        int xi = xs[j];
        rowsW[8 + j] = *(const float2*)(emb + (size_t)xi * 64 + dbase);
    }

    // ---- conv1 (K=7, depthwise) + fold: 8 channels as 4 packed pairs ----
    v2f acc2[4][5];
#pragma unroll
    for (int j = 0; j < 4; ++j) {
        v2f bz = *(const v2f*)(b1c + (2 * sl + rs) * 8 + 2 * j);
#pragma unroll
        for (int m = 0; m < 5; ++m) acc2[j][m] = bz;
    }
    int tA[5];
#pragma unroll
    for (int m = 0; m < 5; ++m) { int t = lane + 64 * m; tA[m] = (t < OUT1) ? t : (OUT1 - 1); }

#pragma unroll 1
    for (int k = 0; k < 7; ++k) {
        v2f wa[4], wb[4];
#pragma unroll
        for (int j = 0; j < 4; ++j) {
            wa[j] = *(const v2f*)(w1t + (dbase * 7 + k) * 8 + 2 * j);
            wb[j] = *(const v2f*)(w1t + ((dbase + 1) * 7 + k) * 8 + 2 * j);
        }
#pragma unroll
        for (int m = 0; m < 5; ++m) {
            float2 v = rowsW[tA[m] + 2 + k];   // j = t-6+k, +8 guard offset
            v2f vx = { v.x, v.x };
            v2f vy = { v.y, v.y };
#pragma unroll
            for (int j = 0; j < 4; ++j) {
                acc2[j][m] = fma2(wa[j], vx, acc2[j][m]);
                acc2[j][m] = fma2(wb[j], vy, acc2[j][m]);
            }
        }
    }

    // ---- p1 guards (rows region dead; p1 aliases it). 64 lanes = 8 ch x 8 slots ----
    {
        int c = lane >> 3, j = lane & 7;
        int pos = (j < 4) ? j : (131 + j);
        p1w[c * 140 + pos] = 0.f;
    }

    // ---- exact order-preserving top-131 per channel, 4 channels interleaved ----
    // group grp covers channels 4grp..4grp+3 = acc2[2grp].x/.y, acc2[2grp+1].x/.y.
    // 16-bit radix with tracked accepted-count ge; no-refine (ge==K) path keeps
    // exactly {u >= pre} with plain compaction. Writes RAW values.
#pragma unroll
    for (int grp = 0; grp < 2; ++grp) {
        uint32_t u[4][5];
#pragma unroll
        for (int m = 0; m < 4; ++m) {          // t = lane+64m < 256 < OUT1 always
            u[0][m] = f2ord(acc2[2 * grp][m].x);
            u[1][m] = f2ord(acc2[2 * grp][m].y);
            u[2][m] = f2ord(acc2[2 * grp + 1][m].x);
            u[3][m] = f2ord(acc2[2 * grp + 1][m].y);
        }
        u[0][4] = (lane < 6) ? f2ord(acc2[2 * grp][4].x) : 0u;   // t=lane+256 < 262
        u[1][4] = (lane < 6) ? f2ord(acc2[2 * grp][4].y) : 0u;
        u[2][4] = (lane < 6) ? f2ord(acc2[2 * grp + 1][4].x) : 0u;
        u[3][4] = (lane < 6) ? f2ord(acc2[2 * grp + 1][4].y) : 0u;

        uint32_t pre[4] = {0u, 0u, 0u, 0u};
        int ge[4] = {0x7FFFFFFF, 0x7FFFFFFF, 0x7FFFFFFF, 0x7FFFFFFF};
#pragma unroll 1
        for (int bit = 31; bit >= 16; --bit) {
            int cnt[4];
#pragma unroll
            for (int c = 0; c < 4; ++c) {
                uint32_t cand = pre[c] | (1u << bit);
                int n = 0;
#pragma unroll
                for (int m = 0; m < 5; ++m) n += __popcll(__ballot(u[c][m] >= cand));
                cnt[c] = n;
            }
#pragma unroll
            for (int c = 0; c < 4; ++c)
                if (cnt[c] >= K1SEL) { pre[c] |= (1u << bit); ge[c] = cnt[c]; }
        }
        float* dst[4];
#pragma unroll
        for (int c = 0; c < 4; ++c) dst[c] = p1w + (4 * grp + c) * 140 + 4;

        if ((ge[0] == K1SEL) && (ge[1] == K1SEL) && (ge[2] == K1SEL) && (ge[3] == K1SEL)) {
            // common path: class boundary exact -> keep = (u >= pre), all ties kept
            int kp[4] = {0, 0, 0, 0};
#pragma unroll
            for (int m = 0; m < 5; ++m) {
#pragma unroll
                for (int c = 0; c < 4; ++c) {
                    unsigned long long km = __ballot(u[c][m] >= pre[c]);
                    int pos = kp[c] + lane_prefix(km);     // order-preserving compaction
                    if (u[c][m] >= pre[c]) dst[c][pos] = ord2f(u[c][m]);
                    kp[c] += __popcll(km);
                }
            }
        } else {
            // rare path: boundary inside a 16-bit class -> refine low bits fully
#pragma unroll 1
            for (int bit = 15; bit >= 0; --bit) {
                int cnt[4];
#pragma unroll
                for (int c = 0; c < 4; ++c) {
                    uint32_t cand = pre[c] | (1u << bit);
                    int n = 0;
#pragma unroll
                    for (int m = 0; m < 5; ++m) n += __popcll(__ballot(u[c][m] >= cand));
                    cnt[c] = n;
                }
#pragma unroll
                for (int c = 0; c < 4; ++c)
                    if (cnt[c] >= K1SEL) pre[c] |= (1u << bit);
            }
            int need[4];
#pragma unroll
            for (int c = 0; c < 4; ++c) {
                int cgt = 0;
#pragma unroll
                for (int m = 0; m < 5; ++m) cgt += __popcll(__ballot(u[c][m] > pre[c]));
                need[c] = K1SEL - cgt;                 // #ties kept (earliest t first)
            }
            int eq[4] = {0, 0, 0, 0}, kp[4] = {0, 0, 0, 0};
#pragma unroll
            for (int m = 0; m < 5; ++m) {
#pragma unroll
                for (int c = 0; c < 4; ++c) {
                    unsigned long long em = __ballot(u[c][m] == pre[c]);
                    int er = eq[c] + lane_prefix(em);
                    bool keep = (u[c][m] > pre[c]) || ((u[c][m] == pre[c]) && (er < need[c]));
                    unsigned long long km = __ballot(keep);
                    int pos = kp[c] + lane_prefix(km);
                    if (keep) dst[c][pos] = ord2f(u[c][m]);
                    eq[c] += __popcll(em); kp[c] += __popcll(km);
                }
            }
        }
    }

    // ---- dense tanh post-pass over the whole p1 region (1120 floats) ----
    // guards are 0 and tanh(0)=0; slot 139 of each channel is never read.
#pragma unroll
    for (int i = 0; i < 17; ++i) {
        int idx = lane + 64 * i;
        p1w[idx] = fast_tanh(p1w[idx]);
    }
    if (lane < 32) {
        int idx = lane + 64 * 17;
        p1w[idx] = fast_tanh(p1w[idx]);
    }

    // ---- conv2 partial: group g = 2sl+rs; 16 f2 as 8 packed pairs ----
    v2f a2v[8][3];
    {
        const v2f* b2v = (const v2f*)(b2c + sl * 16);
#pragma unroll
        for (int j = 0; j < 8; ++j) {
            v2f bz = rs ? (v2f){0.f, 0.f} : b2v[j];   // pre-folded bias counted once
            a2v[j][0] = bz; a2v[j][1] = bz; a2v[j][2] = bz;
        }
    }
    int tB[3];
#pragma unroll
    for (int tm = 0; tm < 3; ++tm) { int t = lane + 64 * tm; tB[tm] = (t < OUT2) ? t : (OUT2 - 1); }

    const int g = 2 * sl + rs;
#pragma unroll 1
    for (int ic = 0; ic < 8; ++ic) {
        const float* src = p1w + ic * 140;   // logical t' = idx - 4
        float win[3][5];                     // straight-line window loads (ds_read2-able)
#pragma unroll
        for (int m = 0; m < 3; ++m) {
            win[m][0] = src[tB[m]];     win[m][1] = src[tB[m] + 1];
            win[m][2] = src[tB[m] + 2]; win[m][3] = src[tB[m] + 3];
            win[m][4] = src[tB[m] + 4];
        }
#pragma unroll
        for (int k = 0; k < 5; ++k) {
            const v2f* wv2 = (const v2f*)(w2t + ((g * 8 + ic) * 5 + k) * 16);
            v2f s0 = { win[0][k], win[0][k] };
            v2f s1 = { win[1][k], win[1][k] };
            v2f s2 = { win[2][k], win[2][k] };
#pragma unroll
            for (int j = 0; j < 8; ++j) {
                v2f w = wv2[j];
                a2v[j][0] = fma2(w, s0, a2v[j][0]);
                a2v[j][1] = fma2(w, s1, a2v[j][1]);
                a2v[j][2] = fma2(w, s2, a2v[j][2]);
            }
        }
    }

    // ---- cross-wave fold (a2 sum) in the pair's dead p1 regions ----
    float* scr = uni + (wv & ~1) * WREG;     // 2240 floats >= 16*137
    __syncthreads();                          // both halves' conv2 done
    if (rs) {
#pragma unroll
        for (int j = 0; j < 8; ++j) {
            scr[(2 * j) * 137 + lane]           = a2v[j][0].x;
            scr[(2 * j + 1) * 137 + lane]       = a2v[j][0].y;
            scr[(2 * j) * 137 + lane + 64]      = a2v[j][1].x;
            scr[(2 * j + 1) * 137 + lane + 64]  = a2v[j][1].y;
            if (lane + 128 < OUT2) {
                scr[(2 * j) * 137 + lane + 128]     = a2v[j][2].x;
                scr[(2 * j + 1) * 137 + lane + 128] = a2v[j][2].y;
            }
        }
    }
    __syncthreads();
    if (!rs) {
#pragma unroll
        for (int j = 0; j < 8; ++j) {
            scr[(2 * j) * 137 + lane]           += a2v[j][0].x;
            scr[(2 * j + 1) * 137 + lane]       += a2v[j][0].y;
            scr[(2 * j) * 137 + lane + 64]      += a2v[j][1].x;
            scr[(2 * j + 1) * 137 + lane + 64]  += a2v[j][1].y;
            if (lane + 128 < OUT2) {
                scr[(2 * j) * 137 + lane + 128]     += a2v[j][2].x;
                scr[(2 * j + 1) * 137 + lane + 128] += a2v[j][2].y;
            }
        }
    }
    __syncthreads();                          // sums visible to both waves

    // ---- top-4 (value desc, tie -> lower t): BOTH waves, 8 lanes per f2 ----
    // 64-bit key = (f2ord(v)<<32) | (0xFFFFFFFF - t); desc == value desc, tie t asc.
    {
        const int f2o = (lane >> 3) + 8 * rs;  // this wave's 8 f2 channels
        const int seg = lane & 7;              // segment of 17 (last has 16)
        const int tstart = seg * 17;
        const int tend = (seg == 7) ? (OUT2 - 119) : 17;
        const float* src = scr + f2o * 137 + tstart;
        const uint32_t tb = 0xFFFFFFFFu - (uint32_t)tstart;
        u64 L0 = 0, L1 = 0, L2 = 0, L3 = 0;    // sentinels (lose to any finite)
#pragma unroll 1
        for (int i = 0; i < 17; ++i) {
            float v = src[(i < tend) ? i : 0];
            u64 kk = ((u64)f2ord(v) << 32) | (u64)(tb - (uint32_t)i);
            if (i >= tend) kk = 0;
            bool b0 = kk > L0, b1 = kk > L1, b2 = kk > L2, b3 = kk > L3;
            L3 = b3 ? (b2 ? L2 : kk) : L3;
            L2 = b2 ? (b1 ? L1 : kk) : L2;
            L1 = b1 ? (b0 ? L0 : kk) : L1;
            L0 = b0 ? kk : L0;
        }
        // merge 8 segments: 3 shfl rounds; r_i = min_{j+l=i} max(A_j,B_l)
#pragma unroll
        for (int d = 1; d <= 4; d <<= 1) {
            u64 M0 = shflx64(L0, d), M1 = shflx64(L1, d);
            u64 M2 = shflx64(L2, d), M3 = shflx64(L3, d);
            u64 r0 = maxu64(L0, M0);
            u64 r1 = minu64(maxu64(L0, M1), maxu64(L1, M0));
            u64 r2 = minu64(minu64(maxu64(L0, M2), maxu64(L1, M1)), maxu64(L2, M0));
            u64 r3k = minu64(minu64(maxu64(L0, M3), maxu64(L1, M2)),
                             minu64(maxu64(L2, M1), maxu64(L3, M0)));
            L0 = r0; L1 = r1; L2 = r2; L3 = r3k;
        }
        if (seg == 0) {
            // reorder by t ascending == low-32 word descending; emit raw (tanh in FC)
#define CSW2(a, bb) { if ((uint32_t)(bb) > (uint32_t)(a)) { u64 tt = (a); (a) = (bb); (bb) = tt; } }
            CSW2(L0, L1); CSW2(L2, L3); CSW2(L0, L2); CSW2(L1, L3); CSW2(L1, L2);
#undef CSW2
            float* qp = &p2loc[(wv >> 1) * 64 + f2o * 4];
            qp[0] = ord2f((uint32_t)(L0 >> 32));
            qp[1] = ord2f((uint32_t)(L1 >> 32));
            qp[2] = ord2f((uint32_t)(L2 >> 32));
            qp[3] = ord2f((uint32_t)(L3 >> 32));
        }
    }
    __syncthreads();

    // ---- FC partial over this block's 128 features (waves 0-1) + atomic out ----
    if (wv < 2) {
        float pv = fast_tanh(p2loc[tid]);
        float part[6];
#pragma unroll
        for (int n = 0; n < 6; ++n) part[n] = pv * fcw[n * 1024 + q8 * 128 + tid];
#pragma unroll
        for (int n = 0; n < 6; ++n) {
            float s = part[n];
#pragma unroll
            for (int off = 32; off > 0; off >>= 1) s += __shfl_xor(s, off, 64);
            if (lane == 0) fred[wv][n] = s;
        }
    }
    __syncthreads();
    if (tid < 6)
        atomicAdd(&out[sample * 6 + tid], fred[0][tid] + fred[1][tid]);
}

extern "C" void kernel_launch(void* const* d_in, const int* in_sizes, int n_in,
                              void* d_out, int out_size, void* d_ws, size_t ws_size,
                              hipStream_t stream) {
    (void)in_sizes; (void)n_in; (void)out_size; (void)ws_size;
    const int*   x   = (const int*)d_in[0];
    const float* emb = (const float*)d_in[1];
    const float* w1  = (const float*)d_in[2];
    const float* b1  = (const float*)d_in[3];
    const float* w2  = (const float*)d_in[4];
    const float* b2  = (const float*)d_in[5];
    const float* fcw = (const float*)d_in[6];
    const float* fcb = (const float*)d_in[7];
    float* outp = (float*)d_out;
    float* wsf  = (float*)d_ws;   // weights+biases: 24576 floats

    dcnn_prep<<<96, 256, 0, stream>>>(w1, b1, w2, b2, fcb, outp, wsf);
    dcnn_main<<<4096, 256, 0, stream>>>(x, emb, fcw, wsf, outp);
}